// Round 3
// baseline (273.136 us; speedup 1.0000x reference)
//
#include <hip/hip_runtime.h>
#include <hip/hip_bf16.h>

typedef unsigned short u16;
typedef unsigned int u32;
typedef short bf16x8 __attribute__((ext_vector_type(8)));
typedef float f32x4 __attribute__((ext_vector_type(4)));

#define DM 1024
#define SEQ 2048
#define MTOK 8192   // 4*2048
#define NQKV 3072

// 0.125 * log2(e): scores land in log2 domain -> exp2f is a single v_exp_f32
#define QSCALE 0.18033688011112042f

__device__ __forceinline__ u16 f2bf(float f) {
  union { float f; unsigned u; } a; a.f = f;
  unsigned r = a.u + 0x7FFFu + ((a.u >> 16) & 1u);
  return (u16)(r >> 16);
}

__device__ __forceinline__ u32 cvt2(float a, float b) {
  __hip_bfloat162 t = __float22bfloat162_rn(make_float2(a, b));
  u32 r; __builtin_memcpy(&r, &t, 4); return r;
}

__device__ __forceinline__ void gload_lds16(const u16* g, u16* l) {
  __builtin_amdgcn_global_load_lds(
      (const __attribute__((address_space(1))) unsigned int*)g,
      (__attribute__((address_space(3))) unsigned int*)l, 16, 0, 0);
}

// ---------------- cast x (fp32 -> bf16), vectorized ----------------
__global__ __launch_bounds__(256) void cast_x_kernel(const float* __restrict__ in,
                                                     u16* __restrict__ out) {
  int i = blockIdx.x * 256 + threadIdx.x;
  float4 v = ((const float4*)in)[i];
  ushort4 o;
  o.x = f2bf(v.x); o.y = f2bf(v.y); o.z = f2bf(v.z); o.w = f2bf(v.w);
  ((ushort4*)out)[i] = o;
}

// ---------------- transpose + cast: in [R][C] fp32 -> out [C][R] bf16 ----------------
__global__ __launch_bounds__(256) void transpose_cast_kernel(const float* __restrict__ in,
                                                             u16* __restrict__ out,
                                                             int R, int C) {
  __shared__ float tile[32][33];
  const int tx = threadIdx.x & 31, ty = threadIdx.x >> 5;
  const int r0 = blockIdx.y << 5, c0 = blockIdx.x << 5;
#pragma unroll
  for (int i = 0; i < 32; i += 8)
    tile[ty + i][tx] = in[(size_t)(r0 + ty + i) * C + (c0 + tx)];
  __syncthreads();
#pragma unroll
  for (int i = 0; i < 32; i += 8)
    out[(size_t)(c0 + ty + i) * R + (r0 + tx)] = f2bf(tile[tx][ty + i]);
}

// ---------------- fill V^T pad rows: row 64 = ones (row-sum row), 65..79 = 0 ----------
__global__ __launch_bounds__(256) void fill_vpad_kernel(u16* __restrict__ vT) {
  const int i = blockIdx.x * 256 + threadIdx.x;   // 524288 ushort4 slots
  const int col4 = i & (SEQ / 4 - 1);
  const int rowg = i >> 9;                        // bh*16 + r
  const int bh = rowg >> 4, r = rowg & 15;
  const u16 val = (r == 0) ? (u16)0x3F80 : (u16)0;
  ushort4 o; o.x = val; o.y = val; o.z = val; o.w = val;
  ((ushort4*)(vT + ((size_t)bh * 80 + 64 + r) * SEQ))[col4] = o;
}

// ---------------- GEMM: A[M][1024] bf16 @ Bt[N][1024]^T, 128x128 tile ----------------
// EPI=0: scatter to q (pre-scaled by QSCALE) [bh][s][d], k [bh][s][d], vT [bh][80][s]
// EPI=1: fp32 out [row][col] + bias
template <int EPI>
__global__ __launch_bounds__(256) void gemm_bt_kernel(
    const u16* __restrict__ A, const u16* __restrict__ Bt,
    const float* __restrict__ bias,
    u16* __restrict__ oq, u16* __restrict__ ok, u16* __restrict__ ovT,
    float* __restrict__ of, int N) {
  const int K = 1024;
  __shared__ alignas(16) u16 As[128 * 32];
  __shared__ alignas(16) u16 Bs[128 * 32];
  const int tid = threadIdx.x;
  const int lane = tid & 63, wid = tid >> 6;
  const int wr = wid >> 1, wc = wid & 1;
  const int l15 = lane & 15, l4 = lane >> 4;
  const int row0 = blockIdx.y << 7, col0 = blockIdx.x << 7;

  f32x4 acc[4][4];
#pragma unroll
  for (int m = 0; m < 4; ++m)
#pragma unroll
    for (int n = 0; n < 4; ++n) acc[m][n] = (f32x4){0.f, 0.f, 0.f, 0.f};

  for (int kt = 0; kt < K; kt += 32) {
    __syncthreads();
#pragma unroll
    for (int i = 0; i < 2; ++i) {
      const int tt = tid + (i << 8);
      const int r = tt >> 2, kk = (tt & 3) << 3;
      gload_lds16(A + (size_t)(row0 + r) * K + kt + kk, As + tt * 8);
      gload_lds16(Bt + (size_t)(col0 + r) * K + kt + kk, Bs + tt * 8);
    }
    __syncthreads();
    bf16x8 a[4], b[4];
#pragma unroll
    for (int m = 0; m < 4; ++m)
      a[m] = *(const bf16x8*)(As + ((wr << 6) + (m << 4) + l15) * 32 + (l4 << 3));
#pragma unroll
    for (int n = 0; n < 4; ++n)
      b[n] = *(const bf16x8*)(Bs + ((wc << 6) + (n << 4) + l15) * 32 + (l4 << 3));
#pragma unroll
    for (int m = 0; m < 4; ++m)
#pragma unroll
      for (int n = 0; n < 4; ++n)
        acc[m][n] = __builtin_amdgcn_mfma_f32_16x16x32_bf16(a[m], b[n], acc[m][n], 0, 0, 0);
  }

#pragma unroll
  for (int n = 0; n < 4; ++n) {
    const int col = col0 + (wc << 6) + (n << 4) + l15;
    const float bv = bias[col];
    if (EPI == 0) {
      const int sel = col >> 10;
      const int h = (col & 1023) >> 6;
      const int d = col & 63;
      const float scl = (sel == 0) ? QSCALE : 1.0f;
#pragma unroll
      for (int m = 0; m < 4; ++m)
#pragma unroll
        for (int r = 0; r < 4; ++r) {
          const int row = row0 + (wr << 6) + (m << 4) + (l4 << 2) + r;
          const int b = row >> 11, s = row & 2047;
          const u16 v = f2bf((acc[m][n][r] + bv) * scl);
          const int bh = (b << 4) + h;
          if (sel == 0)      oq[((size_t)bh * SEQ + s) * 64 + d] = v;
          else if (sel == 1) ok[((size_t)bh * SEQ + s) * 64 + d] = v;
          else               ovT[((size_t)bh * 80 + d) * SEQ + s] = v;
        }
    } else {
#pragma unroll
      for (int m = 0; m < 4; ++m)
#pragma unroll
        for (int r = 0; r < 4; ++r) {
          const int row = row0 + (wr << 6) + (m << 4) + (l4 << 2) + r;
          of[(size_t)row * N + col] = acc[m][n][r] + bv;
        }
    }
  }
}

// ---------------- flash attention: 1 wave, balanced (qi, 63-qi) pair per wave -------
// Swapped layouts: QK -> S^T[k][q], PV -> Z^T[d][q], q = lane&15.
// Row-sum comes from V^T row 64 (= ones) as a 5th Z^T fragment (MFMA does the sum).
// P LDS: [32][64] u16, 16B-unit XOR swizzle (unit ^= row&7) -> conflict-free b128 reads.
__global__ __launch_bounds__(64, 2) void attn_kernel(const u16* __restrict__ qb,
                                                     const u16* __restrict__ kbuf,
                                                     const u16* __restrict__ vT,
                                                     u16* __restrict__ zb) {
  __shared__ alignas(16) u16 pw[32 * 64];
  const int bid = blockIdx.x;
  const int bh = ((bid & 7) << 3) | ((bid >> 3) & 7);   // 8 bh per XCD
  const int pairIdx = bid >> 6;                         // 0..31
  const int b = bh >> 4, h = bh & 15;
  const int lane = threadIdx.x;
  const int l15 = lane & 15, l4 = lane >> 4;
  const int swz = l15 & 7;

  const u16* qp = qb + (size_t)bh * SEQ * 64;
  const u16* kp = kbuf + (size_t)bh * SEQ * 64;
  const u16* vp = vT + (size_t)bh * 80 * SEQ;

  auto loadK = [&](bf16x8 (&kr)[8], int k0) {
#pragma unroll
    for (int nf = 0; nf < 4; ++nf) {
      const u16* p = kp + (size_t)(k0 + (nf << 4) + l15) * 64 + (l4 << 3);
      kr[nf * 2]     = *(const bf16x8*)(p);
      kr[nf * 2 + 1] = *(const bf16x8*)(p + 32);
    }
  };
  auto loadV = [&](bf16x8 (&vr)[10], int k0) {
#pragma unroll
    for (int d = 0; d < 5; ++d) {
      const u16* p = vp + (size_t)((d << 4) + l15) * SEQ + k0 + (l4 << 3);
      vr[d * 2]     = *(const bf16x8*)(p);
      vr[d * 2 + 1] = *(const bf16x8*)(p + 32);
    }
  };

#pragma unroll 1
  for (int seg = 0; seg < 2; ++seg) {
    const int qi = seg ? (63 - pairIdx) : pairIdx;
    const int qrow0 = qi << 5;
    const int nkt = (qi >> 1) + 1;

    bf16x8 aq[2][2];
#pragma unroll
    for (int m = 0; m < 2; ++m)
#pragma unroll
      for (int c = 0; c < 2; ++c)
        aq[m][c] = *(const bf16x8*)(qp + (size_t)(qrow0 + (m << 4) + l15) * 64 + (c << 5) + (l4 << 3));

    f32x4 zo[2][5];
    float mrun[2] = {-INFINITY, -INFINITY};
#pragma unroll
    for (int m = 0; m < 2; ++m)
#pragma unroll
      for (int d = 0; d < 5; ++d) zo[m][d] = (f32x4){0.f, 0.f, 0.f, 0.f};

    auto tile = [&](bf16x8 (&kc)[8], bf16x8 (&kn)[8], int kt) {
      const int k0 = kt << 6;
      // prefetch next K tile (hidden under this tile's softmax+PV)
      if (kt + 1 < nkt) loadK(kn, k0 + 64);
      // V for this tile (consumed at the end; hidden under QK+softmax)
      bf16x8 vv[10];
      loadV(vv, k0);
      // ---- QK^T (swapped) ----
      f32x4 s[2][4];
#pragma unroll
      for (int m = 0; m < 2; ++m)
#pragma unroll
        for (int nf = 0; nf < 4; ++nf) s[m][nf] = (f32x4){0.f, 0.f, 0.f, 0.f};
#pragma unroll
      for (int nf = 0; nf < 4; ++nf)
#pragma unroll
        for (int m = 0; m < 2; ++m) {
          s[m][nf] = __builtin_amdgcn_mfma_f32_16x16x32_bf16(kc[nf * 2], aq[m][0], s[m][nf], 0, 0, 0);
          s[m][nf] = __builtin_amdgcn_mfma_f32_16x16x32_bf16(kc[nf * 2 + 1], aq[m][1], s[m][nf], 0, 0, 0);
        }
      // ---- causal mask on diagonal tile ----
      if (kt == nkt - 1) {
#pragma unroll
        for (int m = 0; m < 2; ++m) {
          const int qtok = qrow0 + (m << 4) + l15;
#pragma unroll
          for (int nf = 0; nf < 4; ++nf)
#pragma unroll
            for (int r = 0; r < 4; ++r) {
              const int ktok = k0 + (nf << 4) + (l4 << 2) + r;
              if (ktok > qtok) s[m][nf][r] = -INFINITY;
            }
        }
      }
      // ---- online softmax: stats at q=l15, row max via 2 shfl; sum via MFMA ----
#pragma unroll
      for (int m = 0; m < 2; ++m) {
        float mx = s[m][0][0];
#pragma unroll
        for (int nf = 0; nf < 4; ++nf)
#pragma unroll
          for (int r = 0; r < 4; ++r) mx = fmaxf(mx, s[m][nf][r]);
        mx = fmaxf(mx, __shfl_xor(mx, 16));
        mx = fmaxf(mx, __shfl_xor(mx, 32));
        if (__ballot(mx > mrun[m])) {   // exact defer: skip when row max unchanged
          const float mnew = fmaxf(mrun[m], mx);
          const float alpha = exp2f(mrun[m] - mnew);
          mrun[m] = mnew;
#pragma unroll
          for (int d = 0; d < 5; ++d) zo[m][d] *= alpha;
        }
        const int row = (m << 4) + l15;
#pragma unroll
        for (int nf = 0; nf < 4; ++nf) {
          f32x4 p;
#pragma unroll
          for (int r = 0; r < 4; ++r) p[r] = exp2f(s[m][nf][r] - mrun[m]);
          const int phys = ((nf << 1) + (l4 >> 1)) ^ swz;
          uint2 o; o.x = cvt2(p[0], p[1]); o.y = cvt2(p[2], p[3]);
          *(uint2*)(pw + row * 64 + phys * 8 + ((l4 & 1) << 2)) = o;
        }
      }
      // ---- P reads (swizzled, conflict-free) + PV ----
      bf16x8 pa[2][2];
#pragma unroll
      for (int m = 0; m < 2; ++m)
#pragma unroll
        for (int c = 0; c < 2; ++c) {
          const int phys = ((c << 2) + l4) ^ swz;
          pa[m][c] = *(const bf16x8*)(pw + ((m << 4) + l15) * 64 + phys * 8);
        }
#pragma unroll
      for (int d = 0; d < 5; ++d) {
        zo[0][d] = __builtin_amdgcn_mfma_f32_16x16x32_bf16(vv[d * 2], pa[0][0], zo[0][d], 0, 0, 0);
        zo[0][d] = __builtin_amdgcn_mfma_f32_16x16x32_bf16(vv[d * 2 + 1], pa[0][1], zo[0][d], 0, 0, 0);
        zo[1][d] = __builtin_amdgcn_mfma_f32_16x16x32_bf16(vv[d * 2], pa[1][0], zo[1][d], 0, 0, 0);
        zo[1][d] = __builtin_amdgcn_mfma_f32_16x16x32_bf16(vv[d * 2 + 1], pa[1][1], zo[1][d], 0, 0, 0);
      }
    };

    bf16x8 kra[8], krb[8];
    loadK(kra, 0);
    int kt = 0;
    for (; kt + 2 <= nkt; kt += 2) {
      tile(kra, krb, kt);
      tile(krb, kra, kt + 1);
    }
    if (kt < nkt) tile(kra, krb, kt);

    // ---- epilogue: denominator = Z^T row 64 (ones-row sum), broadcast via shfl ----
#pragma unroll
    for (int m = 0; m < 2; ++m) {
      const float sm = __shfl(zo[m][4][0], l15);
      const float inv = 1.0f / sm;
      const int q = qrow0 + (m << 4) + l15;
#pragma unroll
      for (int d = 0; d < 4; ++d) {
        uint2 o;
        o.x = cvt2(zo[m][d][0] * inv, zo[m][d][1] * inv);
        o.y = cvt2(zo[m][d][2] * inv, zo[m][d][3] * inv);
        *(uint2*)(zb + (((size_t)b * SEQ + q) * 16 + h) * 64 + (d << 4) + (l4 << 2)) = o;
      }
    }
  }
}

// ---------------- launch ----------------
extern "C" void kernel_launch(void* const* d_in, const int* in_sizes, int n_in,
                              void* d_out, int out_size, void* d_ws, size_t ws_size,
                              hipStream_t stream) {
  const float* x     = (const float*)d_in[0];
  const float* w_qkv = (const float*)d_in[1];
  const float* b_qkv = (const float*)d_in[2];
  const float* w_out = (const float*)d_in[3];
  const float* b_out = (const float*)d_in[4];
  float* out = (float*)d_out;

  char* ws = (char*)d_ws;
  u16* xb    = (u16*)ws;  ws += (size_t)MTOK * DM * 2;
  u16* wqkvT = (u16*)ws;  ws += (size_t)NQKV * DM * 2;
  u16* woutT = (u16*)ws;  ws += (size_t)DM * DM * 2;
  u16* qb    = (u16*)ws;  ws += (size_t)MTOK * DM * 2;
  u16* kb    = (u16*)ws;  ws += (size_t)MTOK * DM * 2;
  u16* vTb   = (u16*)ws;  ws += (size_t)64 * 80 * SEQ * 2;   // 80 rows per bh (64 V + ones + pad)
  u16* zbuf  = (u16*)ws;  ws += (size_t)MTOK * DM * 2;

  cast_x_kernel<<<MTOK * DM / 1024, 256, 0, stream>>>(x, xb);
  transpose_cast_kernel<<<dim3(NQKV / 32, DM / 32), 256, 0, stream>>>(w_qkv, wqkvT, DM, NQKV);
  transpose_cast_kernel<<<dim3(DM / 32, DM / 32), 256, 0, stream>>>(w_out, woutT, DM, DM);
  fill_vpad_kernel<<<2048, 256, 0, stream>>>(vTb);

  gemm_bt_kernel<0><<<dim3(NQKV / 128, MTOK / 128), 256, 0, stream>>>(
      xb, wqkvT, b_qkv, qb, kb, vTb, nullptr, NQKV);

  attn_kernel<<<2048, 64, 0, stream>>>(qb, kb, vTb, zbuf);

  gemm_bt_kernel<1><<<dim3(DM / 128, MTOK / 128), 256, 0, stream>>>(
      zbuf, woutT, b_out, nullptr, nullptr, nullptr, out, DM);
}

// Round 4
// 212.572 us; speedup vs baseline: 1.2849x; 1.2849x over previous
//
#include <hip/hip_runtime.h>
#include <hip/hip_bf16.h>

typedef unsigned short u16;
typedef unsigned int u32;
typedef short bf16x8 __attribute__((ext_vector_type(8)));
typedef float f32x4 __attribute__((ext_vector_type(4)));

#define DM 1024
#define SEQ 2048
#define MTOK 8192   // 4*2048
#define NQKV 3072

// 0.125 * log2(e): scores land in log2 domain -> exp2f is a single v_exp_f32
#define QSCALE 0.18033688011112042f

__device__ __forceinline__ u16 f2bf(float f) {
  union { float f; unsigned u; } a; a.f = f;
  unsigned r = a.u + 0x7FFFu + ((a.u >> 16) & 1u);
  return (u16)(r >> 16);
}

__device__ __forceinline__ u32 cvt2(float a, float b) {
  __hip_bfloat162 t = __float22bfloat162_rn(make_float2(a, b));
  u32 r; __builtin_memcpy(&r, &t, 4); return r;
}

__device__ __forceinline__ void gload_lds16(const u16* g, u16* l) {
  __builtin_amdgcn_global_load_lds(
      (const __attribute__((address_space(1))) unsigned int*)g,
      (__attribute__((address_space(3))) unsigned int*)l, 16, 0, 0);
}

// ---------------- cast x (fp32 -> bf16), vectorized ----------------
__global__ __launch_bounds__(256) void cast_x_kernel(const float* __restrict__ in,
                                                     u16* __restrict__ out) {
  int i = blockIdx.x * 256 + threadIdx.x;
  float4 v = ((const float4*)in)[i];
  ushort4 o;
  o.x = f2bf(v.x); o.y = f2bf(v.y); o.z = f2bf(v.z); o.w = f2bf(v.w);
  ((ushort4*)out)[i] = o;
}

// ---------------- transpose + cast: in [R][C] fp32 -> out [C][R] bf16 ----------------
__global__ __launch_bounds__(256) void transpose_cast_kernel(const float* __restrict__ in,
                                                             u16* __restrict__ out,
                                                             int R, int C) {
  __shared__ float tile[32][33];
  const int tx = threadIdx.x & 31, ty = threadIdx.x >> 5;
  const int r0 = blockIdx.y << 5, c0 = blockIdx.x << 5;
#pragma unroll
  for (int i = 0; i < 32; i += 8)
    tile[ty + i][tx] = in[(size_t)(r0 + ty + i) * C + (c0 + tx)];
  __syncthreads();
#pragma unroll
  for (int i = 0; i < 32; i += 8)
    out[(size_t)(c0 + ty + i) * R + (r0 + tx)] = f2bf(tile[tx][ty + i]);
}

// ---------------- fill V^T pad rows: row 64 = ones (row-sum row), 65..79 = 0 ----------
__global__ __launch_bounds__(256) void fill_vpad_kernel(u16* __restrict__ vT) {
  const int i = blockIdx.x * 256 + threadIdx.x;   // 524288 ushort4 slots
  const int col4 = i & (SEQ / 4 - 1);
  const int rowg = i >> 9;                        // bh*16 + r
  const int bh = rowg >> 4, r = rowg & 15;
  const u16 val = (r == 0) ? (u16)0x3F80 : (u16)0;
  ushort4 o; o.x = val; o.y = val; o.z = val; o.w = val;
  ((ushort4*)(vT + ((size_t)bh * 80 + 64 + r) * SEQ))[col4] = o;
}

// ---------------- GEMM: A[M][1024] bf16 @ Bt[N][1024]^T, 128x128 tile ----------------
template <int EPI>
__global__ __launch_bounds__(256) void gemm_bt_kernel(
    const u16* __restrict__ A, const u16* __restrict__ Bt,
    const float* __restrict__ bias,
    u16* __restrict__ oq, u16* __restrict__ ok, u16* __restrict__ ovT,
    float* __restrict__ of, int N) {
  const int K = 1024;
  __shared__ alignas(16) u16 As[128 * 32];
  __shared__ alignas(16) u16 Bs[128 * 32];
  const int tid = threadIdx.x;
  const int lane = tid & 63, wid = tid >> 6;
  const int wr = wid >> 1, wc = wid & 1;
  const int l15 = lane & 15, l4 = lane >> 4;
  const int row0 = blockIdx.y << 7, col0 = blockIdx.x << 7;

  f32x4 acc[4][4];
#pragma unroll
  for (int m = 0; m < 4; ++m)
#pragma unroll
    for (int n = 0; n < 4; ++n) acc[m][n] = (f32x4){0.f, 0.f, 0.f, 0.f};

  for (int kt = 0; kt < K; kt += 32) {
    __syncthreads();
#pragma unroll
    for (int i = 0; i < 2; ++i) {
      const int tt = tid + (i << 8);
      const int r = tt >> 2, kk = (tt & 3) << 3;
      gload_lds16(A + (size_t)(row0 + r) * K + kt + kk, As + tt * 8);
      gload_lds16(Bt + (size_t)(col0 + r) * K + kt + kk, Bs + tt * 8);
    }
    __syncthreads();
    bf16x8 a[4], b[4];
#pragma unroll
    for (int m = 0; m < 4; ++m)
      a[m] = *(const bf16x8*)(As + ((wr << 6) + (m << 4) + l15) * 32 + (l4 << 3));
#pragma unroll
    for (int n = 0; n < 4; ++n)
      b[n] = *(const bf16x8*)(Bs + ((wc << 6) + (n << 4) + l15) * 32 + (l4 << 3));
#pragma unroll
    for (int m = 0; m < 4; ++m)
#pragma unroll
      for (int n = 0; n < 4; ++n)
        acc[m][n] = __builtin_amdgcn_mfma_f32_16x16x32_bf16(a[m], b[n], acc[m][n], 0, 0, 0);
  }

#pragma unroll
  for (int n = 0; n < 4; ++n) {
    const int col = col0 + (wc << 6) + (n << 4) + l15;
    const float bv = bias[col];
    if (EPI == 0) {
      const int sel = col >> 10;
      const int h = (col & 1023) >> 6;
      const int d = col & 63;
      const float scl = (sel == 0) ? QSCALE : 1.0f;
#pragma unroll
      for (int m = 0; m < 4; ++m)
#pragma unroll
        for (int r = 0; r < 4; ++r) {
          const int row = row0 + (wr << 6) + (m << 4) + (l4 << 2) + r;
          const int b = row >> 11, s = row & 2047;
          const u16 v = f2bf((acc[m][n][r] + bv) * scl);
          const int bh = (b << 4) + h;
          if (sel == 0)      oq[((size_t)bh * SEQ + s) * 64 + d] = v;
          else if (sel == 1) ok[((size_t)bh * SEQ + s) * 64 + d] = v;
          else               ovT[((size_t)bh * 80 + d) * SEQ + s] = v;
        }
    } else {
#pragma unroll
      for (int m = 0; m < 4; ++m)
#pragma unroll
        for (int r = 0; r < 4; ++r) {
          const int row = row0 + (wr << 6) + (m << 4) + (l4 << 2) + r;
          of[(size_t)row * N + col] = acc[m][n][r] + bv;
        }
    }
  }
}

// ---------------- flash attention: 8 waves/block, K/V staged in LDS -----------------
// Block: 512 threads = 8 waves, 256 consecutive q rows (32 per wave), kt 0..nkt-1.
// Per tile: stage K[64][64] + V^T[80][64] (next tile) to LDS via global_load_lds
// (linear dest, pre-swizzled source: chunk ^= row&7), compute from current buffer,
// one __syncthreads() per tile (drains vmcnt -> staging complete).
// Swapped layouts: QK -> S^T[k][q], PV -> Z^T[d][q], q = lane&15.
// Row-sum via ones-row (V^T row 64) as a 5th Z^T fragment.
__global__ __launch_bounds__(512, 4) void attn_kernel(const u16* __restrict__ qb,
                                                      const u16* __restrict__ kbuf,
                                                      const u16* __restrict__ vT,
                                                      u16* __restrict__ zb) {
  __shared__ alignas(16) u16 Ks[2][64 * 64];   // 16 KB
  __shared__ alignas(16) u16 Vs[2][80 * 64];   // 20 KB
  __shared__ alignas(16) u16 Ps[8][32 * 64];   // 32 KB

  const int bid = blockIdx.x;
  const int xcd = bid & 7;
  const int idx = bid >> 3;
  const int bh = (xcd << 3) | (idx & 7);        // 8 bh per XCD
  const int qpart = idx >> 3;                   // 0..7
  const int qseg = (qpart < 4) ? (7 - qpart) : (qpart - 4);  // CU pairs sum to 7
  const int b = bh >> 4, h = bh & 15;

  const int tid = threadIdx.x;
  const int lane = tid & 63, wid = tid >> 6;
  const int l15 = lane & 15, l4 = lane >> 4;
  const int swz = l15 & 7;

  const u16* qp = qb + (size_t)bh * SEQ * 64;
  const u16* kp = kbuf + (size_t)bh * SEQ * 64;
  const u16* vp = vT + (size_t)bh * 80 * SEQ;

  const int qw0 = qseg * 256 + (wid << 5);      // this wave's first q row
  const int nkt = (qseg + 1) << 2;              // block k-tiles
  const int ktmax = (qseg << 2) + (wid >> 1);   // this wave's diagonal tile

  // staging source pointers (pre-swizzled global: chunk ^= row&7)
  const int srow = tid >> 3, schk = tid & 7;
  const u16* ksrc  = kp + (size_t)srow * 64 + ((schk ^ (srow & 7)) << 3);
  const u16* vsrc  = vp + (size_t)srow * SEQ + ((schk ^ (srow & 7)) << 3);
  const u16* vsrc2 = vp + (size_t)(64 + srow) * SEQ + ((schk ^ (srow & 7)) << 3);

  auto stage = [&](int buf, int kt) {
    gload_lds16(ksrc + (size_t)kt * 4096, &Ks[buf][0] + tid * 8);
    gload_lds16(vsrc + (size_t)kt * 64, &Vs[buf][0] + tid * 8);
    if (tid < 128) gload_lds16(vsrc2 + (size_t)kt * 64, &Vs[buf][0] + 4096 + tid * 8);
  };

  // Q fragments (registers, once)
  bf16x8 aq[2][2];
#pragma unroll
  for (int m = 0; m < 2; ++m)
#pragma unroll
    for (int c = 0; c < 2; ++c)
      aq[m][c] = *(const bf16x8*)(qp + (size_t)(qw0 + (m << 4) + l15) * 64 + (c << 5) + (l4 << 3));

  f32x4 zo[2][5];
  float mrun[2] = {-INFINITY, -INFINITY};
#pragma unroll
  for (int m = 0; m < 2; ++m)
#pragma unroll
    for (int d = 0; d < 5; ++d) zo[m][d] = (f32x4){0.f, 0.f, 0.f, 0.f};

  u16* pw = &Ps[wid][0];

  stage(0, 0);
  __syncthreads();

  int cur = 0;
  for (int kt = 0; kt < nkt; ++kt) {
    if (kt + 1 < nkt) stage(cur ^ 1, kt + 1);

    if (kt <= ktmax) {
      const int k0 = kt << 6;
      const u16* kb_ = &Ks[cur][0];
      const u16* vb_ = &Vs[cur][0];
      // ---- QK^T (swapped): A = K frags from LDS (swizzled read) ----
      f32x4 s[2][4];
#pragma unroll
      for (int m = 0; m < 2; ++m)
#pragma unroll
        for (int nf = 0; nf < 4; ++nf) s[m][nf] = (f32x4){0.f, 0.f, 0.f, 0.f};
#pragma unroll
      for (int nf = 0; nf < 4; ++nf) {
        const u16* kr = kb_ + ((nf << 4) + l15) * 64;
        const bf16x8 kf0 = *(const bf16x8*)(kr + ((l4 ^ swz) << 3));
        const bf16x8 kf1 = *(const bf16x8*)(kr + (((l4 + 4) ^ swz) << 3));
#pragma unroll
        for (int m = 0; m < 2; ++m) {
          s[m][nf] = __builtin_amdgcn_mfma_f32_16x16x32_bf16(kf0, aq[m][0], s[m][nf], 0, 0, 0);
          s[m][nf] = __builtin_amdgcn_mfma_f32_16x16x32_bf16(kf1, aq[m][1], s[m][nf], 0, 0, 0);
        }
      }
      // ---- causal mask on this wave's diagonal tile ----
      if (kt == ktmax) {
#pragma unroll
        for (int m = 0; m < 2; ++m) {
          const int qtok = qw0 + (m << 4) + l15;
#pragma unroll
          for (int nf = 0; nf < 4; ++nf)
#pragma unroll
            for (int r = 0; r < 4; ++r) {
              const int ktok = k0 + (nf << 4) + (l4 << 2) + r;
              if (ktok > qtok) s[m][nf][r] = -INFINITY;
            }
        }
      }
      // ---- online softmax: stats at q=l15; sum via ones-row MFMA ----
#pragma unroll
      for (int m = 0; m < 2; ++m) {
        float mx = s[m][0][0];
#pragma unroll
        for (int nf = 0; nf < 4; ++nf)
#pragma unroll
          for (int r = 0; r < 4; ++r) mx = fmaxf(mx, s[m][nf][r]);
        mx = fmaxf(mx, __shfl_xor(mx, 16));
        mx = fmaxf(mx, __shfl_xor(mx, 32));
        if (__ballot(mx > mrun[m])) {   // exact defer: skip when row max unchanged
          const float mnew = fmaxf(mrun[m], mx);
          const float alpha = exp2f(mrun[m] - mnew);
          mrun[m] = mnew;
#pragma unroll
          for (int d = 0; d < 5; ++d) zo[m][d] *= alpha;
        }
        const int row = (m << 4) + l15;
#pragma unroll
        for (int nf = 0; nf < 4; ++nf) {
          f32x4 p;
#pragma unroll
          for (int r = 0; r < 4; ++r) p[r] = exp2f(s[m][nf][r] - mrun[m]);
          const int phys = ((nf << 1) + (l4 >> 1)) ^ swz;
          uint2 o; o.x = cvt2(p[0], p[1]); o.y = cvt2(p[2], p[3]);
          *(u32*)(pw + row * 64 + phys * 8 + ((l4 & 1) << 2)) = o.x;
          *(u32*)(pw + row * 64 + phys * 8 + ((l4 & 1) << 2) + 2) = o.y;
        }
      }
      // ---- P reads (swizzled) + PV from LDS V ----
      bf16x8 pa[2][2];
#pragma unroll
      for (int m = 0; m < 2; ++m)
#pragma unroll
        for (int c = 0; c < 2; ++c) {
          const int phys = ((c << 2) + l4) ^ swz;
          pa[m][c] = *(const bf16x8*)(pw + ((m << 4) + l15) * 64 + phys * 8);
        }
#pragma unroll
      for (int d = 0; d < 5; ++d) {
        const u16* vr = vb_ + ((d << 4) + l15) * 64;
        const bf16x8 vf0 = *(const bf16x8*)(vr + ((l4 ^ swz) << 3));
        const bf16x8 vf1 = *(const bf16x8*)(vr + (((l4 + 4) ^ swz) << 3));
        zo[0][d] = __builtin_amdgcn_mfma_f32_16x16x32_bf16(vf0, pa[0][0], zo[0][d], 0, 0, 0);
        zo[0][d] = __builtin_amdgcn_mfma_f32_16x16x32_bf16(vf1, pa[0][1], zo[0][d], 0, 0, 0);
        zo[1][d] = __builtin_amdgcn_mfma_f32_16x16x32_bf16(vf0, pa[1][0], zo[1][d], 0, 0, 0);
        zo[1][d] = __builtin_amdgcn_mfma_f32_16x16x32_bf16(vf1, pa[1][1], zo[1][d], 0, 0, 0);
      }
    }
    __syncthreads();
    cur ^= 1;
  }

  // ---- epilogue: denominator = Z^T row 64 (ones-row sum), broadcast via shfl ----
#pragma unroll
  for (int m = 0; m < 2; ++m) {
    const float sm = __shfl(zo[m][4][0], l15);
    const float inv = 1.0f / sm;
    const int q = qw0 + (m << 4) + l15;
#pragma unroll
    for (int d = 0; d < 4; ++d) {
      uint2 o;
      o.x = cvt2(zo[m][d][0] * inv, zo[m][d][1] * inv);
      o.y = cvt2(zo[m][d][2] * inv, zo[m][d][3] * inv);
      *(uint2*)(zb + (((size_t)b * SEQ + q) * 16 + h) * 64 + (d << 4) + (l4 << 2)) = o;
    }
  }
}

// ---------------- launch ----------------
extern "C" void kernel_launch(void* const* d_in, const int* in_sizes, int n_in,
                              void* d_out, int out_size, void* d_ws, size_t ws_size,
                              hipStream_t stream) {
  const float* x     = (const float*)d_in[0];
  const float* w_qkv = (const float*)d_in[1];
  const float* b_qkv = (const float*)d_in[2];
  const float* w_out = (const float*)d_in[3];
  const float* b_out = (const float*)d_in[4];
  float* out = (float*)d_out;

  char* ws = (char*)d_ws;
  u16* xb    = (u16*)ws;  ws += (size_t)MTOK * DM * 2;
  u16* wqkvT = (u16*)ws;  ws += (size_t)NQKV * DM * 2;
  u16* woutT = (u16*)ws;  ws += (size_t)DM * DM * 2;
  u16* qb    = (u16*)ws;  ws += (size_t)MTOK * DM * 2;
  u16* kb    = (u16*)ws;  ws += (size_t)MTOK * DM * 2;
  u16* vTb   = (u16*)ws;  ws += (size_t)64 * 80 * SEQ * 2;
  u16* zbuf  = (u16*)ws;  ws += (size_t)MTOK * DM * 2;

  cast_x_kernel<<<MTOK * DM / 1024, 256, 0, stream>>>(x, xb);
  transpose_cast_kernel<<<dim3(NQKV / 32, DM / 32), 256, 0, stream>>>(w_qkv, wqkvT, DM, NQKV);
  transpose_cast_kernel<<<dim3(DM / 32, DM / 32), 256, 0, stream>>>(w_out, woutT, DM, DM);
  fill_vpad_kernel<<<2048, 256, 0, stream>>>(vTb);

  gemm_bt_kernel<0><<<dim3(NQKV / 128, MTOK / 128), 256, 0, stream>>>(
      xb, wqkvT, b_qkv, qb, kb, vTb, nullptr, NQKV);

  attn_kernel<<<512, 512, 0, stream>>>(qb, kb, vTb, zbuf);

  gemm_bt_kernel<1><<<dim3(DM / 128, MTOK / 128), 256, 0, stream>>>(
      zbuf, woutT, b_out, nullptr, nullptr, nullptr, out, DM);
}